// Round 12
// baseline (10579.788 us; speedup 1.0000x reference)
//
#include <hip/hip_runtime.h>
#include <math.h>

#define TENC 256
#define NIE  6
#define LH   68    // h row stride (floats): 16B-aligned rows, 2-way bank alias = free
#define WSTR 68    // weight row stride: jg-offsets land on banks {0,24,16,8} = conflict-free

// ---- LDS: 2*52224 (sW1+sU1) + 528 + 3*17408 (rotating h pool) = 157,200 B ----
__shared__ float sW1[192 * WSTR];   // [(j*3+g)*WSTR + k]
__shared__ float sU1[192 * WSTR];
__shared__ float sHd[132];          // [0:64) Wcv, [64:128) Won
__shared__ float shs[3][64 * LH];   // rotating pool: {h0, h1, free}

// fast activations: v_exp + v_rcp. Proven r4/r6: VALU -13.5pts, absmax identical.
__device__ __forceinline__ float sigm_(float x) {
    return __builtin_amdgcn_rcpf(1.0f + __expf(-x));
}
__device__ __forceinline__ float tanh_(float x) {
    float t = __expf(2.0f * x);
    return (t - 1.0f) * __builtin_amdgcn_rcpf(t + 1.0f);
}

__device__ __forceinline__ void fma4(float& acc, const float4& a, const float4& b) {
    acc = fmaf(a.x, b.x, acc);
    acc = fmaf(a.y, b.y, acc);
    acc = fmaf(a.z, b.z, acc);
    acc = fmaf(a.w, b.w, acc);
}

__device__ __forceinline__ void stage_w1(const float* __restrict__ W1,
                                         const float* __restrict__ U1) {
    for (int s = threadIdx.x; s < 12288; s += 1024) {
        int k = s & 63, row = s >> 6;          // row = g*64 + j (global layout)
        int g = row >> 6, j = row & 63;
        int d = (j * 3 + g) * WSTR + k;        // j-major in LDS
        sW1[d] = W1[s];
        sU1[d] = U1[s];
    }
}

// layer 0: W0 in regs, U0 from global (L2-hot), h from hb (LDS). 1 j x 4 batches.
// (1024-thread tiling: per-lane work halved vs r10 -> 16 waves, 4/SIMD.)
template<int KIN>
__device__ __forceinline__ void layer0_c(const float* __restrict__ U0,
                                         const float* w0r, const float* w0z,
                                         const float* w0n,          // [KIN] regs
                                         const float* xin,          // [4*KIN] regs
                                         float b_r, float b_z,
                                         float b_nx, float b_nh,
                                         int j, int bl,
                                         const float* __restrict__ hb,
                                         float hn[4])
{
    float ar[4], az[4], anx[4], anh[4];
#pragma unroll
    for (int g = 0; g < 4; ++g) {
        ar[g] = b_r; az[g] = b_z; anx[g] = b_nx; anh[g] = b_nh;
    }
#pragma unroll
    for (int g = 0; g < 4; ++g)
#pragma unroll
        for (int k = 0; k < KIN; ++k) {
            ar[g]  = fmaf(w0r[k], xin[g * KIN + k], ar[g]);
            az[g]  = fmaf(w0z[k], xin[g * KIN + k], az[g]);
            anx[g] = fmaf(w0n[k], xin[g * KIN + k], anx[g]);
        }
    const float* u0 = U0 + (size_t)j * 64;
    const float* hr0 = hb + bl * LH;
#pragma unroll 2
    for (int kc = 0; kc < 64; kc += 4) {
        float4 hv[4];
#pragma unroll
        for (int g = 0; g < 4; ++g)
            hv[g] = *(const float4*)(hr0 + g * (16 * LH) + kc);
        float4 r0 = *(const float4*)(u0 + kc);
        float4 z0 = *(const float4*)(u0 + 4096 + kc);
        float4 n0 = *(const float4*)(u0 + 8192 + kc);
#pragma unroll
        for (int g = 0; g < 4; ++g) {
            fma4(ar[g], r0, hv[g]); fma4(az[g], z0, hv[g]); fma4(anh[g], n0, hv[g]);
        }
    }
#pragma unroll
    for (int g = 0; g < 4; ++g) {
        float hold = hb[(bl + 16 * g) * LH + j];
        float r = sigm_(ar[g]);
        float z = sigm_(az[g]);
        float n = tanh_(fmaf(r, anh[g], anx[g]));
        hn[g] = fmaf(z, hold - n, n);
    }
}

// layer 1: x = xb rows (LDS), h = hb rows (LDS), W1/U1 from LDS. 1 j x 4 batches.
__device__ __forceinline__ void layer1_c(float b_r, float b_z,
                                         float b_nx, float b_nh,
                                         int j, int bl,
                                         const float* __restrict__ xb,
                                         const float* __restrict__ hb,
                                         float hn[4])
{
    float ar[4], az[4], anx[4], anh[4];
#pragma unroll
    for (int g = 0; g < 4; ++g) {
        ar[g] = b_r; az[g] = b_z; anx[g] = b_nx; anh[g] = b_nh;
    }
    const float* wb = sW1 + (j * 3) * WSTR;
    const float* ub = sU1 + (j * 3) * WSTR;
    const float* xr0 = xb + bl * LH;
    const float* hr0 = hb + bl * LH;
#pragma unroll 2
    for (int kc = 0; kc < 64; kc += 4) {
        float4 xv[4], hv[4];
#pragma unroll
        for (int g = 0; g < 4; ++g) {
            xv[g] = *(const float4*)(xr0 + g * (16 * LH) + kc);
            hv[g] = *(const float4*)(hr0 + g * (16 * LH) + kc);
        }
        float4 wr = *(const float4*)(wb + kc);
        float4 wz = *(const float4*)(wb + WSTR + kc);
        float4 wn = *(const float4*)(wb + 2 * WSTR + kc);
        float4 ur = *(const float4*)(ub + kc);
        float4 uz = *(const float4*)(ub + WSTR + kc);
        float4 un = *(const float4*)(ub + 2 * WSTR + kc);
#pragma unroll
        for (int g = 0; g < 4; ++g) {
            fma4(ar[g], wr, xv[g]);  fma4(ar[g], ur, hv[g]);
            fma4(az[g], wz, xv[g]);  fma4(az[g], uz, hv[g]);
            fma4(anx[g], wn, xv[g]); fma4(anh[g], un, hv[g]);
        }
    }
#pragma unroll
    for (int g = 0; g < 4; ++g) {
        float hold = hb[(bl + 16 * g) * LH + j];
        float r = sigm_(ar[g]);
        float z = sigm_(az[g]);
        float n = tanh_(fmaf(r, anh[g], anx[g]));
        hn[g] = fmaf(z, hold - n, n);
    }
}

// 1024-thread occupancy experiment: r6/r9/r10 all converge to ~8.5ms at 73%
// VALU with 2 waves/SIMD -> idle is in-loop latency, not barriers. 16 waves
// (4/SIMD) halve per-lane work and double latency-hiding. Rotating 3-buffer
// 2-barrier schedule and sched_barrier(0) layer split carried from r10.
extern "C" __global__ void __launch_bounds__(1024)
ccseq_kernel(const float* __restrict__ x, const int* __restrict__ p_tlen,
             const float* __restrict__ eW0, const float* __restrict__ eU0,
             const float* __restrict__ eBi0, const float* __restrict__ eBh0,
             const float* __restrict__ eW1, const float* __restrict__ eU1,
             const float* __restrict__ eBi1, const float* __restrict__ eBh1,
             const float* __restrict__ dW0, const float* __restrict__ dU0,
             const float* __restrict__ dBi0, const float* __restrict__ dBh0,
             const float* __restrict__ dW1, const float* __restrict__ dU1,
             const float* __restrict__ dBi1, const float* __restrict__ dBh1,
             const float* __restrict__ Won, const float* __restrict__ bon,
             const float* __restrict__ Wcv, const float* __restrict__ bcv,
             float* __restrict__ out)
{
    const int tid  = threadIdx.x;
    const int lane = tid & 63;
    const int wv   = tid >> 6;          // 0..15
    const int jg   = lane >> 4;         // 0..3
    const int bl   = lane & 15;         // 0..15
    const int j    = wv * 4 + jg;       // this lane's single hidden unit
    const int tlen = p_tlen[0];

    if (tid < 64) { sHd[tid] = Wcv[tid]; sHd[64 + tid] = Won[tid]; }
    for (int i = tid; i < 64 * LH; i += 1024) {
        shs[0][i] = 0.0f; shs[1][i] = 0.0f; shs[2][i] = 0.0f;
    }
    stage_w1(eW1, eU1);
    __syncthreads();

    // ---- hoisted per-lane constants (encoder) ----
    float w0r[NIE], w0z[NIE], w0n[NIE];
#pragma unroll
    for (int k = 0; k < NIE; ++k) {
        w0r[k] = eW0[j * NIE + k];
        w0z[k] = eW0[(64 + j) * NIE + k];
        w0n[k] = eW0[(128 + j) * NIE + k];
    }
    const float eb_r  = eBi0[j] + eBh0[j];
    const float eb_z  = eBi0[64 + j] + eBh0[64 + j];
    const float eb_nx = eBi0[128 + j];
    const float eb_nh = eBh0[128 + j];
    const float e1_r  = eBi1[j] + eBh1[j];
    const float e1_z  = eBi1[64 + j] + eBh1[64 + j];
    const float e1_nx = eBi1[128 + j];
    const float e1_nh = eBh1[128 + j];

    const size_t bstr = (size_t)TENC * NIE;
    const float* xb[4];
#pragma unroll
    for (int g = 0; g < 4; ++g)
        xb[g] = x + (size_t)(blockIdx.x * 64 + bl + 16 * g) * bstr;

    // ---------------- encoder prologue: h0(0) = gru0(x(0), 0) ----------------
    float xc[4 * NIE];
    float hn[4], hn0[4];
#pragma unroll
    for (int g = 0; g < 4; ++g)
#pragma unroll
        for (int k = 0; k < NIE; ++k) xc[g * NIE + k] = xb[g][k];

    layer0_c<NIE>(eU0, w0r, w0z, w0n, xc, eb_r, eb_z, eb_nx, eb_nh,
                  j, bl, shs[0] /*zeros*/, hn0);
#pragma unroll
    for (int g = 0; g < 4; ++g)
        shs[1][(bl + 16 * g) * LH + j] = hn0[g];
    __syncthreads();                            // h0(0) published
    int ih0 = 1, ih1 = 2, ifr = 0;              // h1(-1)=zeros in shs[2]

    // ---------------- encoder: 2 barriers/step ----------------
    for (int t = 0; t < TENC; ++t) {
        if (t + 1 < TENC) {
#pragma unroll
            for (int g = 0; g < 4; ++g)
#pragma unroll
                for (int k = 0; k < NIE; ++k)
                    xc[g * NIE + k] = xb[g][(t + 1) * NIE + k];
        }

        layer1_c(e1_r, e1_z, e1_nx, e1_nh, j, bl, shs[ih0], shs[ih1], hn);

        // separate the two layers' register-pressure regions (r9 spill fix)
        __builtin_amdgcn_sched_barrier(0);

        if (t + 1 < TENC) {
            layer0_c<NIE>(eU0, w0r, w0z, w0n, xc, eb_r, eb_z, eb_nx, eb_nh,
                          j, bl, shs[ih0], hn0);
#pragma unroll
            for (int g = 0; g < 4; ++g)
                shs[ifr][(bl + 16 * g) * LH + j] = hn0[g];
        }
        __syncthreads();                       // A: h0(t+1) published; h1 reads drained
#pragma unroll
        for (int g = 0; g < 4; ++g)
            shs[ih1][(bl + 16 * g) * LH + j] = hn[g];   // h1(t) in place
        __syncthreads();                       // B: h1(t) published

        if (t + 1 < TENC) { int o = ih0; ih0 = ifr; ifr = o; }
    }
    // state: shs[ih0]=h0(255), shs[ih1]=h1(255), shs[ifr] free

    // ---------------- swap to decoder weights ----------------
    stage_w1(dW1, dU1);                        // safe: sW1/sU1 reads drained by barrier B
    const float v0r = dW0[j], v0z = dW0[64 + j], v0n = dW0[128 + j];
    const float db_r  = dBi0[j] + dBh0[j];
    const float db_z  = dBi0[64 + j] + dBh0[64 + j];
    const float db_nx = dBi0[128 + j];
    const float db_nh = dBh0[128 + j];
    const float d1_r  = dBi1[j] + dBh1[j];
    const float d1_z  = dBi1[64 + j] + dBh1[64 + j];
    const float d1_nx = dBi1[128 + j];
    const float d1_nh = dBh1[128 + j];
    const float hbc = bcv[0], hbo = bon[0];
    __syncthreads();

    // ---------------- decoder: 2 barriers/step (rotating buffers) ----------------
    float prev[4] = {0.0f, 0.0f, 0.0f, 0.0f};
    for (int t = 0; t < tlen; ++t) {
        layer0_c<1>(dU0, &v0r, &v0z, &v0n, prev, db_r, db_z, db_nx, db_nh,
                    j, bl, shs[ih0], hn);
#pragma unroll
        for (int g = 0; g < 4; ++g)
            shs[ifr][(bl + 16 * g) * LH + j] = hn[g];
        __syncthreads();                       // A: h0_dec(t) published

        layer1_c(d1_r, d1_z, d1_nx, d1_nh, j, bl, shs[ifr], shs[ih1], hn);
#pragma unroll
        for (int g = 0; g < 4; ++g)
            shs[ih0][(bl + 16 * g) * LH + j] = hn[g];   // h1_dec(t) into dead h0-old
        __syncthreads();                       // B: h1_dec(t) published

        // heads: every lane computes its own 4 batches (no exchange needed)
        float cv[4] = {hbc, hbc, hbc, hbc};
        float lg[4] = {hbo, hbo, hbo, hbo};
        const float* hr0 = shs[ih0] + bl * LH;
#pragma unroll 2
        for (int kc = 0; kc < 64; kc += 4) {
            float4 wc = *(const float4*)(sHd + kc);
            float4 wo = *(const float4*)(sHd + 64 + kc);
#pragma unroll
            for (int g = 0; g < 4; ++g) {
                float4 h4 = *(const float4*)(hr0 + g * (16 * LH) + kc);
                fma4(cv[g], wc, h4);
                fma4(lg[g], wo, h4);
            }
        }
#pragma unroll
        for (int g = 0; g < 4; ++g)
            prev[g] = (lg[g] > 0.0f) ? cv[g] : 0.0f;   // sigmoid(lg)>0.5 <=> lg>0
        if (tid < 16) {
#pragma unroll
            for (int g = 0; g < 4; ++g)
                out[(size_t)(blockIdx.x * 64 + bl + 16 * g) * tlen + t] = prev[g];
        }
        int o0 = ih0, o1 = ih1;
        ih0 = ifr; ih1 = o0; ifr = o1;
    }
}

extern "C" void kernel_launch(void* const* d_in, const int* in_sizes, int n_in,
                              void* d_out, int out_size, void* d_ws, size_t ws_size,
                              hipStream_t stream)
{
    (void)n_in; (void)out_size; (void)d_ws; (void)ws_size;
    const float* x    = (const float*)d_in[0];
    const int*   tl   = (const int*)d_in[1];
    const float* eW0  = (const float*)d_in[2];
    const float* eU0  = (const float*)d_in[3];
    const float* eBi0 = (const float*)d_in[4];
    const float* eBh0 = (const float*)d_in[5];
    const float* eW1  = (const float*)d_in[6];
    const float* eU1  = (const float*)d_in[7];
    const float* eBi1 = (const float*)d_in[8];
    const float* eBh1 = (const float*)d_in[9];
    const float* dW0  = (const float*)d_in[10];
    const float* dU0  = (const float*)d_in[11];
    const float* dBi0 = (const float*)d_in[12];
    const float* dBh0 = (const float*)d_in[13];
    const float* dW1  = (const float*)d_in[14];
    const float* dU1  = (const float*)d_in[15];
    const float* dBi1 = (const float*)d_in[16];
    const float* dBh1 = (const float*)d_in[17];
    const float* Won  = (const float*)d_in[18];
    const float* bon  = (const float*)d_in[19];
    const float* Wcv  = (const float*)d_in[20];
    const float* bcv  = (const float*)d_in[21];

    const int B    = in_sizes[0] / (TENC * NIE);  // 16384
    const int nblk = B / 64;                      // 256 blocks, 1/CU

    ccseq_kernel<<<dim3(nblk), dim3(1024), 0, stream>>>(
        x, tl, eW0, eU0, eBi0, eBh0, eW1, eU1, eBi1, eBh1,
        dW0, dU0, dBi0, dBh0, dW1, dU1, dBi1, dBh1,
        Won, bon, Wcv, bcv, (float*)d_out);
}